// Round 2
// baseline (1860.114 us; speedup 1.0000x reference)
//
#include <hip/hip_runtime.h>
#include <math.h>

#define P_   3
#define L_   6
#define CPL_ 32
#define C_   192
#define HID_ 64

__device__ __forceinline__ float bf2f(unsigned short u) {
    return __uint_as_float(((unsigned int)u) << 16);
}

// ---------------------------------------------------------------------------
// Transpose planes (N,P,C,256,256) f32  ->  (N,P,65536,C) bf16
// ---------------------------------------------------------------------------
__global__ __launch_bounds__(256) void transpose_kernel(
    const float* __restrict__ in, unsigned short* __restrict__ out)
{
    __shared__ __align__(16) float tile[32][196];   // rows 784B (16B mult)
    const int np   = blockIdx.x >> 11;
    const int pix0 = (blockIdx.x & 2047) << 5;
    const float* src = in + (size_t)np * C_ * 65536;
    uint2* dst = (uint2*)(out + (size_t)np * 65536 * C_);
    const int t = threadIdx.x;

    #pragma unroll
    for (int it = 0; it < 24; ++it) {               // 192c * 32px / 256
        int idx = it * 256 + t;
        int Cc  = idx >> 5;
        int px  = idx & 31;
        tile[px][Cc] = src[(size_t)Cc * 65536 + pix0 + px];  // coalesced
    }
    __syncthreads();
    #pragma unroll
    for (int it = 0; it < 6; ++it) {                // 32px * 48 c-quads / 256
        int idx = it * 256 + t;
        int cq  = idx % 48;
        int px  = idx / 48;
        float4 fv = *(const float4*)&tile[px][4 * cq];
        unsigned int u0 = __float_as_uint(fv.x), u1 = __float_as_uint(fv.y);
        unsigned int u2 = __float_as_uint(fv.z), u3 = __float_as_uint(fv.w);
        u0 = (u0 + 0x7fffu + ((u0 >> 16) & 1)) >> 16;   // RNE to bf16
        u1 = (u1 + 0x7fffu + ((u1 >> 16) & 1)) >> 16;
        u2 = (u2 + 0x7fffu + ((u2 >> 16) & 1)) >> 16;
        u3 = (u3 + 0x7fffu + ((u3 >> 16) & 1)) >> 16;
        uint2 pk;
        pk.x = u0 | (u1 << 16);
        pk.y = u2 | (u3 << 16);
        dst[(size_t)(pix0 + px) * 48 + cq] = pk;        // coalesced
    }
}

// ---------------------------------------------------------------------------
// One wave handles PT points. Lane ell owns channels {ell, ell+64, ell+128}.
// All LDS is wave-private (slot-indexed) -> no __syncthreads needed.
// ---------------------------------------------------------------------------
template <int PT, bool TR>
__global__ __launch_bounds__(256) void point_kernel(
    const unsigned short* __restrict__ planes_bf,  // TR : (NP,HW,C) bf16
    const float* __restrict__ planes_f32,          // !TR: (NP,C,HW) f32
    const float* __restrict__ coords,
    const float* __restrict__ w1,       // (L, CPL, HID)
    const float* __restrict__ b1,       // (L, HID)
    const float* __restrict__ w2,       // (L, HID, 5)
    const float* __restrict__ b2,       // (L, 5)
    const float* __restrict__ betap,
    float* __restrict__ out)            // (N*M, 17)
{
    __shared__ __align__(16) float feat_s[4 * PT][C_];
    __shared__ __align__(16) float dz_s[4 * PT][L_ * HID_];
    __shared__ __align__(16) float o_s[4 * PT][24];

    const int wave = threadIdx.x >> 6;
    const int lane = threadIdx.x & 63;
    const int pt0  = (blockIdx.x * 4 + wave) * PT;
    const int n0   = pt0 >> 16;          // PT=2, pt0 even -> same n for both

    float cx[PT], cy[PT], cz[PT];
    float wx0[PT][3], wx1[PT][3], wy0[PT][3], wy1[PT][3];
    int   pixi[PT][3][4];
    float vmk[PT][3][4];

    #pragma unroll
    for (int i = 0; i < PT; ++i) {
        int pt = pt0 + i;
        cx[i] = coords[pt * 3 + 0];
        cy[i] = coords[pt * 3 + 1];
        cz[i] = coords[pt * 3 + 2];
        float pjx[3] = {cx[i], cx[i], cz[i]};
        float pjy[3] = {cy[i], cz[i], cy[i]};
        #pragma unroll
        for (int p = 0; p < 3; ++p) {
            float px = (pjx[p] + 1.0f) * 128.0f - 0.5f;
            float py = (pjy[p] + 1.0f) * 128.0f - 0.5f;
            float x0f = floorf(px), y0f = floorf(py);
            wx1[i][p] = px - x0f; wx0[i][p] = 1.0f - wx1[i][p];
            wy1[i][p] = py - y0f; wy0[i][p] = 1.0f - wy1[i][p];
            int x0 = (int)x0f, y0 = (int)y0f;
            int x1 = x0 + 1,  y1 = y0 + 1;
            int xc0 = min(max(x0, 0), 255), xc1 = min(max(x1, 0), 255);
            int yc0 = min(max(y0, 0), 255), yc1 = min(max(y1, 0), 255);
            float vx0 = (x0 >= 0 && x0 < 256) ? 1.f : 0.f;
            float vx1 = (x1 >= 0 && x1 < 256) ? 1.f : 0.f;
            float vy0 = (y0 >= 0 && y0 < 256) ? 1.f : 0.f;
            float vy1 = (y1 >= 0 && y1 < 256) ? 1.f : 0.f;
            pixi[i][p][0] = yc0 * 256 + xc0; vmk[i][p][0] = vx0 * vy0;
            pixi[i][p][1] = yc0 * 256 + xc1; vmk[i][p][1] = vx1 * vy0;
            pixi[i][p][2] = yc1 * 256 + xc0; vmk[i][p][2] = vx0 * vy1;
            pixi[i][p][3] = yc1 * 256 + xc1; vmk[i][p][3] = vx1 * vy1;
        }
    }

    // ---- gathers: PT x 3 planes x 4 corners x 3 channels/lane ----
    float g[PT][3][4][3];
    #pragma unroll
    for (int i = 0; i < PT; ++i)
        #pragma unroll
        for (int p = 0; p < 3; ++p)
            #pragma unroll
            for (int ij = 0; ij < 4; ++ij)
                #pragma unroll
                for (int k = 0; k < 3; ++k) {
                    int Cc = lane + 64 * k;
                    float v;
                    if (TR) {
                        size_t a = ((size_t)((n0 * 3 + p) * 65536 + pixi[i][p][ij])) * C_ + Cc;
                        v = bf2f(planes_bf[a]);
                    } else {
                        size_t a = ((size_t)((n0 * 3 + p) * C_ + Cc)) * 65536 + pixi[i][p][ij];
                        v = planes_f32[a];
                    }
                    g[i][p][ij][k] = v * vmk[i][p][ij];
                }

    // ---- feat ----
    #pragma unroll
    for (int i = 0; i < PT; ++i) {
        int slot = wave * PT + i;
        #pragma unroll
        for (int k = 0; k < 3; ++k) {
            float f = 0.f;
            #pragma unroll
            for (int p = 0; p < 3; ++p) {
                f += wx0[i][p] * wy0[i][p] * g[i][p][0][k]
                   + wx1[i][p] * wy0[i][p] * g[i][p][1][k]
                   + wx0[i][p] * wy1[i][p] * g[i][p][2][k]
                   + wx1[i][p] * wy1[i][p] * g[i][p][3][k];
            }
            feat_s[slot][lane + 64 * k] = f * (1.0f / 3.0f);
        }
    }
    asm volatile("s_waitcnt lgkmcnt(0)" ::: "memory");

    // ---- MLP forward (lane == hidden unit), weights shared across PT ----
    #pragma unroll
    for (int l = 0; l < L_; ++l) {
        float w1r[CPL_];
        #pragma unroll
        for (int c = 0; c < CPL_; ++c)
            w1r[c] = w1[(l * CPL_ + c) * HID_ + lane];
        float b1l = b1[l * HID_ + lane];
        const float* w2l = w2 + (l * HID_ + lane) * 5;
        float w20 = w2l[0], w21 = w2l[1], w22 = w2l[2], w23 = w2l[3];
        float b2v = b2[l * 5 + (lane & 3)];

        #pragma unroll
        for (int i = 0; i < PT; ++i) {
            int slot = wave * PT + i;
            float z = b1l;
            #pragma unroll
            for (int q = 0; q < 8; ++q) {
                float4 fv = *(const float4*)&feat_s[slot][l * CPL_ + 4 * q];
                z = fmaf(fv.x, w1r[4 * q + 0], z);
                z = fmaf(fv.y, w1r[4 * q + 1], z);
                z = fmaf(fv.z, w1r[4 * q + 2], z);
                z = fmaf(fv.w, w1r[4 * q + 3], z);
            }
            float e  = expf(-fabsf(z));
            float sp = fmaxf(z, 0.f) + log1pf(e);
            float sg = ((z > 0.f) ? 1.0f : e) / (1.0f + e);   // sigmoid(z)
            dz_s[slot][l * HID_ + lane] = sg * w20;
            float o0 = sp * w20, o1 = sp * w21, o2 = sp * w22, o3 = sp * w23;
            #pragma unroll
            for (int s = 1; s < 64; s <<= 1) {
                o0 += __shfl_xor(o0, s, 64);
                o1 += __shfl_xor(o1, s, 64);
                o2 += __shfl_xor(o2, s, 64);
                o3 += __shfl_xor(o3, s, 64);
            }
            if ((lane >> 2) == l) {
                int j = lane & 3;
                float ov = (j == 0) ? o0 : (j == 1) ? o1 : (j == 2) ? o2 : o3;
                o_s[slot][lane] = ov + b2v;
            }
        }
    }
    asm volatile("s_waitcnt lgkmcnt(0)" ::: "memory");

    // ---- dfeat: df[c] = sum_h dz[l(c),h] * w1[c,h]  (w1 stream shared) ----
    float df[PT][3];
    #pragma unroll
    for (int i = 0; i < PT; ++i)
        #pragma unroll
        for (int k = 0; k < 3; ++k) df[i][k] = 0.f;

    #pragma unroll
    for (int k = 0; k < 3; ++k) {
        int cg = lane + 64 * k;
        const float* w1r = w1 + cg * HID_;
        int row = (cg >> 5) * HID_;
        #pragma unroll
        for (int h4 = 0; h4 < 16; ++h4) {
            float4 wv = *(const float4*)(w1r + 4 * h4);
            #pragma unroll
            for (int i = 0; i < PT; ++i) {
                float4 dv = *(const float4*)&dz_s[wave * PT + i][row + 4 * h4];
                df[i][k] = fmaf(wv.x, dv.x, df[i][k]);
                df[i][k] = fmaf(wv.y, dv.y, df[i][k]);
                df[i][k] = fmaf(wv.z, dv.z, df[i][k]);
                df[i][k] = fmaf(wv.w, dv.w, df[i][k]);
            }
        }
    }

    const float beta = betap[0];

    // ---- per-point gradient dots + epilogue ----
    #pragma unroll
    for (int i = 0; i < PT; ++i) {
        int slot = wave * PT + i;
        int pt   = pt0 + i;
        float ax[3] = {0.f, 0.f, 0.f};
        float ay[3] = {0.f, 0.f, 0.f};
        #pragma unroll
        for (int k = 0; k < 3; ++k)
            #pragma unroll
            for (int p = 0; p < 3; ++p) {
                ax[p] = fmaf(df[i][k], wy0[i][p] * (g[i][p][1][k] - g[i][p][0][k])
                                     + wy1[i][p] * (g[i][p][3][k] - g[i][p][2][k]), ax[p]);
                ay[p] = fmaf(df[i][k], wx0[i][p] * (g[i][p][2][k] - g[i][p][0][k])
                                     + wx1[i][p] * (g[i][p][3][k] - g[i][p][1][k]), ay[p]);
            }
        #pragma unroll
        for (int s = 1; s < 64; s <<= 1) {
            ax[0] += __shfl_xor(ax[0], s, 64);
            ax[1] += __shfl_xor(ax[1], s, 64);
            ax[2] += __shfl_xor(ax[2], s, 64);
            ay[0] += __shfl_xor(ay[0], s, 64);
            ay[1] += __shfl_xor(ay[1], s, 64);
            ay[2] += __shfl_xor(ay[2], s, 64);
        }
        const float F = 128.0f / 3.0f;
        float gcx = F * (ax[0] + ax[1]);
        float gcy = F * (ay[0] + ay[2]);
        float gcz = F * (ay[1] + ax[2]);

        float olev[L_][4];
        #pragma unroll
        for (int l = 0; l < L_; ++l) {
            float4 ov = *(const float4*)&o_s[slot][4 * l];
            olev[l][0] = ov.x; olev[l][1] = ov.y;
            olev[l][2] = ov.z; olev[l][3] = ov.w;
        }

        float r    = sqrtf(cx[i] * cx[i] + cy[i] * cy[i] + cz[i] * cz[i]);
        float smpl = r - 0.5f;
        float delta = 0.f;
        #pragma unroll
        for (int l = 0; l < L_; ++l) delta += olev[l][0];
        float sdf = smpl + delta;

        float ls[L_], sigma = 0.f;
        #pragma unroll
        for (int l = 0; l < L_; ++l) {
            float s = olev[l][0] + smpl;
            ls[l] = (1.0f / (1.0f + expf(s / beta))) / beta;
            sigma += ls[l];
        }
        float inv = 1.0f / (sigma + 1e-8f);
        float sem[L_];
        #pragma unroll
        for (int l = 0; l < L_; ++l) sem[l] = ls[l] * inv;

        float r0 = 0.f, r1 = 0.f, r2 = 0.f;
        #pragma unroll
        for (int l = 0; l < L_; ++l) {
            r0 = fmaf(olev[l][1], sem[l], r0);
            r1 = fmaf(olev[l][2], sem[l], r1);
            r2 = fmaf(olev[l][3], sem[l], r2);
        }
        float rgb0 = (1.0f / (1.0f + expf(-r0))) * 1.002f - 0.001f;
        float rgb1 = (1.0f / (1.0f + expf(-r1))) * 1.002f - 0.001f;
        float rgb2 = (1.0f / (1.0f + expf(-r2))) * 1.002f - 0.001f;

        float rinv = 1.0f / (r + 1e-8f);
        if (lane < 17) {
            float v =
                (lane == 0)  ? sdf :
                (lane == 1)  ? sigma :
                (lane == 2)  ? rgb0 :
                (lane == 3)  ? rgb1 :
                (lane == 4)  ? rgb2 :
                (lane == 5)  ? sem[0] :
                (lane == 6)  ? sem[1] :
                (lane == 7)  ? sem[2] :
                (lane == 8)  ? sem[3] :
                (lane == 9)  ? sem[4] :
                (lane == 10) ? sem[5] :
                (lane == 11) ? gcx + cx[i] * rinv :
                (lane == 12) ? gcy + cy[i] * rinv :
                (lane == 13) ? gcz + cz[i] * rinv :
                (lane == 14) ? gcx :
                (lane == 15) ? gcy : gcz;
            out[(size_t)pt * 17 + lane] = v;
        }
    }
}

extern "C" void kernel_launch(void* const* d_in, const int* in_sizes, int n_in,
                              void* d_out, int out_size, void* d_ws, size_t ws_size,
                              hipStream_t stream)
{
    const float* planes = (const float*)d_in[0];
    const float* coords = (const float*)d_in[1];
    const float* w1     = (const float*)d_in[2];
    const float* b1     = (const float*)d_in[3];
    const float* w2     = (const float*)d_in[4];
    const float* b2     = (const float*)d_in[5];
    const float* beta   = (const float*)d_in[6];
    float* out = (float*)d_out;

    const size_t need = (size_t)6 * 65536 * C_ * sizeof(unsigned short); // 151 MB
    const int nblocks = 131072 / (4 * 2);   // 4 waves/block, 2 pts/wave
    if (ws_size >= need) {
        unsigned short* tp = (unsigned short*)d_ws;
        transpose_kernel<<<6 * 2048, 256, 0, stream>>>(planes, tp);
        point_kernel<2, true><<<nblocks, 256, 0, stream>>>(
            tp, nullptr, coords, w1, b1, w2, b2, beta, out);
    } else {
        point_kernel<2, false><<<nblocks, 256, 0, stream>>>(
            nullptr, planes, coords, w1, b1, w2, b2, beta, out);
    }
}

// Round 3
// 1364.957 us; speedup vs baseline: 1.3628x; 1.3628x over previous
//
#include <hip/hip_runtime.h>
#include <math.h>

#define P_   3
#define L_   6
#define CPL_ 32
#define C_   192
#define HID_ 64

__device__ __forceinline__ float bf2f(unsigned short u) {
    return __uint_as_float(((unsigned int)u) << 16);
}

// ---------------------------------------------------------------------------
// Transpose planes (N,P,C,256,256) f32  ->  (N,P,65536,C) bf16
// (unchanged from round 2 — proven)
// ---------------------------------------------------------------------------
__global__ __launch_bounds__(256) void transpose_kernel(
    const float* __restrict__ in, unsigned short* __restrict__ out)
{
    __shared__ __align__(16) float tile[32][196];
    const int np   = blockIdx.x >> 11;
    const int pix0 = (blockIdx.x & 2047) << 5;
    const float* src = in + (size_t)np * C_ * 65536;
    uint2* dst = (uint2*)(out + (size_t)np * 65536 * C_);
    const int t = threadIdx.x;

    #pragma unroll
    for (int it = 0; it < 24; ++it) {
        int idx = it * 256 + t;
        int Cc  = idx >> 5;
        int px  = idx & 31;
        tile[px][Cc] = src[(size_t)Cc * 65536 + pix0 + px];
    }
    __syncthreads();
    #pragma unroll
    for (int it = 0; it < 6; ++it) {
        int idx = it * 256 + t;
        int cq  = idx % 48;
        int px  = idx / 48;
        float4 fv = *(const float4*)&tile[px][4 * cq];
        unsigned int u0 = __float_as_uint(fv.x), u1 = __float_as_uint(fv.y);
        unsigned int u2 = __float_as_uint(fv.z), u3 = __float_as_uint(fv.w);
        u0 = (u0 + 0x7fffu + ((u0 >> 16) & 1)) >> 16;
        u1 = (u1 + 0x7fffu + ((u1 >> 16) & 1)) >> 16;
        u2 = (u2 + 0x7fffu + ((u2 >> 16) & 1)) >> 16;
        u3 = (u3 + 0x7fffu + ((u3 >> 16) & 1)) >> 16;
        uint2 pk;
        pk.x = u0 | (u1 << 16);
        pk.y = u2 | (u3 << 16);
        dst[(size_t)(pix0 + px) * 48 + cq] = pk;
    }
}

// ---------------------------------------------------------------------------
// One wave per point. Lane ell owns channels {ell, ell+64, ell+128}.
// LDS is wave-private (slot = wave) -> only wave-local lgkmcnt waits needed.
// ---------------------------------------------------------------------------
template <bool TR>
__global__ __launch_bounds__(256, 4) void point_kernel(
    const unsigned short* __restrict__ planes_bf,  // TR : (NP,HW,C) bf16
    const float* __restrict__ planes_f32,          // !TR: (NP,C,HW) f32
    const float* __restrict__ coords,
    const float* __restrict__ w1,       // (L, CPL, HID)
    const float* __restrict__ b1,       // (L, HID)
    const float* __restrict__ w2,       // (L, HID, 5)
    const float* __restrict__ b2,       // (L, 5)
    const float* __restrict__ betap,
    float* __restrict__ out)            // (N*M, 17)
{
    __shared__ __align__(16) float feat_s[4][C_];
    __shared__ __align__(16) float dz_s[4][L_ * HID_];
    __shared__ __align__(16) float o_s[4][24];

    const int wave  = threadIdx.x >> 6;
    const int lane  = threadIdx.x & 63;
    const int point = blockIdx.x * 4 + wave;
    const int n     = point >> 16;

    const float cx = coords[point * 3 + 0];
    const float cy = coords[point * 3 + 1];
    const float cz = coords[point * 3 + 2];

    const float pjx[3] = {cx, cx, cz};
    const float pjy[3] = {cy, cz, cy};

    float wx0[3], wx1[3], wy0[3], wy1[3];
    int   pixi[3][4];
    float vmk[3][4];
    #pragma unroll
    for (int p = 0; p < 3; ++p) {
        float px = (pjx[p] + 1.0f) * 128.0f - 0.5f;
        float py = (pjy[p] + 1.0f) * 128.0f - 0.5f;
        float x0f = floorf(px), y0f = floorf(py);
        wx1[p] = px - x0f; wx0[p] = 1.0f - wx1[p];
        wy1[p] = py - y0f; wy0[p] = 1.0f - wy1[p];
        int x0 = (int)x0f, y0 = (int)y0f;
        int x1 = x0 + 1,  y1 = y0 + 1;
        int xc0 = min(max(x0, 0), 255), xc1 = min(max(x1, 0), 255);
        int yc0 = min(max(y0, 0), 255), yc1 = min(max(y1, 0), 255);
        float vx0 = (x0 >= 0 && x0 < 256) ? 1.f : 0.f;
        float vx1 = (x1 >= 0 && x1 < 256) ? 1.f : 0.f;
        float vy0 = (y0 >= 0 && y0 < 256) ? 1.f : 0.f;
        float vy1 = (y1 >= 0 && y1 < 256) ? 1.f : 0.f;
        pixi[p][0] = yc0 * 256 + xc0; vmk[p][0] = vx0 * vy0;
        pixi[p][1] = yc0 * 256 + xc1; vmk[p][1] = vx1 * vy0;
        pixi[p][2] = yc1 * 256 + xc0; vmk[p][2] = vx0 * vy1;
        pixi[p][3] = yc1 * 256 + xc1; vmk[p][3] = vx1 * vy1;
    }

    // ---- gather: 3 planes x 4 corners x 3 channels/lane ----
    float g[3][4][3];
    #pragma unroll
    for (int p = 0; p < 3; ++p)
        #pragma unroll
        for (int ij = 0; ij < 4; ++ij)
            #pragma unroll
            for (int k = 0; k < 3; ++k) {
                int Cc = lane + 64 * k;
                float v;
                if (TR) {
                    size_t a = ((size_t)((n * 3 + p) * 65536 + pixi[p][ij])) * C_ + Cc;
                    v = bf2f(planes_bf[a]);
                } else {
                    size_t a = ((size_t)((n * 3 + p) * C_ + Cc)) * 65536 + pixi[p][ij];
                    v = planes_f32[a];
                }
                g[p][ij][k] = v * vmk[p][ij];
            }

    // ---- feat = mean over planes of bilinear combos ----
    #pragma unroll
    for (int k = 0; k < 3; ++k) {
        float f = 0.f;
        #pragma unroll
        for (int p = 0; p < 3; ++p) {
            f += wx0[p] * wy0[p] * g[p][0][k] + wx1[p] * wy0[p] * g[p][1][k]
               + wx0[p] * wy1[p] * g[p][2][k] + wx1[p] * wy1[p] * g[p][3][k];
        }
        feat_s[wave][lane + 64 * k] = f * (1.0f / 3.0f);
    }
    asm volatile("s_waitcnt lgkmcnt(0)" ::: "memory");

    // ---- MLP forward: lane == hidden unit ----
    #pragma unroll
    for (int l = 0; l < L_; ++l) {
        float b1l = b1[l * HID_ + lane];
        const float* w2l = w2 + (l * HID_ + lane) * 5;
        float w20 = w2l[0], w21 = w2l[1], w22 = w2l[2], w23 = w2l[3];

        float z0 = b1l, z1 = 0.f;
        #pragma unroll
        for (int q = 0; q < 8; ++q) {
            float4 fv = *(const float4*)&feat_s[wave][l * CPL_ + 4 * q];
            z0 = fmaf(fv.x, w1[(l * CPL_ + 4 * q + 0) * HID_ + lane], z0);
            z1 = fmaf(fv.y, w1[(l * CPL_ + 4 * q + 1) * HID_ + lane], z1);
            z0 = fmaf(fv.z, w1[(l * CPL_ + 4 * q + 2) * HID_ + lane], z0);
            z1 = fmaf(fv.w, w1[(l * CPL_ + 4 * q + 3) * HID_ + lane], z1);
        }
        float z  = z0 + z1;
        float e  = expf(-fabsf(z));
        float sp = fmaxf(z, 0.f) + log1pf(e);
        float sg = ((z > 0.f) ? 1.0f : e) / (1.0f + e);   // sigmoid(z)
        dz_s[wave][l * HID_ + lane] = sg * w20;

        float o0 = sp * w20, o1 = sp * w21, o2 = sp * w22, o3 = sp * w23;
        // pack-2 / pack-2 / merge / butterfly reduction (20 instr vs 48)
        float u  = (lane & 1) ? o1 : o0;
        float uw = (lane & 1) ? o0 : o1;
        u += __shfl_xor(uw, 1, 64);
        float v  = (lane & 1) ? o3 : o2;
        float vw = (lane & 1) ? o2 : o3;
        v += __shfl_xor(vw, 1, 64);
        float tt = (lane & 2) ? v : u;
        float tw = (lane & 2) ? u : v;
        tt += __shfl_xor(tw, 2, 64);
        tt += __shfl_xor(tt, 4, 64);
        tt += __shfl_xor(tt, 8, 64);
        tt += __shfl_xor(tt, 16, 64);
        tt += __shfl_xor(tt, 32, 64);
        // lane now holds full sum of o_{lane&3}; lane l*4+j owns (l,j)
        if ((lane >> 2) == l)
            o_s[wave][lane] = tt + b2[l * 5 + (lane & 3)];
    }
    asm volatile("s_waitcnt lgkmcnt(0)" ::: "memory");

    // ---- dfeat: df[c] = sum_h dz[l(c),h] * w1[c,h] ----
    float df[3];
    #pragma unroll
    for (int k = 0; k < 3; ++k) {
        int cg = lane + 64 * k;
        const float* w1r = w1 + cg * HID_;
        const float* dzr = &dz_s[wave][(cg >> 5) * HID_];
        float a0 = 0.f, a1 = 0.f;
        #pragma unroll
        for (int h4 = 0; h4 < 16; ++h4) {
            float4 wv = *(const float4*)(w1r + 4 * h4);
            float4 dv = *(const float4*)(dzr + 4 * h4);
            a0 = fmaf(wv.x, dv.x, a0);
            a1 = fmaf(wv.y, dv.y, a1);
            a0 = fmaf(wv.z, dv.z, a0);
            a1 = fmaf(wv.w, dv.w, a1);
        }
        df[k] = a0 + a1;
    }

    // ---- gradient dots (register-resident corners) ----
    float ax[3] = {0.f, 0.f, 0.f};
    float ay[3] = {0.f, 0.f, 0.f};
    #pragma unroll
    for (int k = 0; k < 3; ++k)
        #pragma unroll
        for (int p = 0; p < 3; ++p) {
            ax[p] = fmaf(df[k], wy0[p] * (g[p][1][k] - g[p][0][k])
                               + wy1[p] * (g[p][3][k] - g[p][2][k]), ax[p]);
            ay[p] = fmaf(df[k], wx0[p] * (g[p][2][k] - g[p][0][k])
                               + wx1[p] * (g[p][3][k] - g[p][1][k]), ay[p]);
        }
    #pragma unroll
    for (int s = 1; s < 64; s <<= 1) {
        ax[0] += __shfl_xor(ax[0], s, 64);
        ax[1] += __shfl_xor(ax[1], s, 64);
        ax[2] += __shfl_xor(ax[2], s, 64);
        ay[0] += __shfl_xor(ay[0], s, 64);
        ay[1] += __shfl_xor(ay[1], s, 64);
        ay[2] += __shfl_xor(ay[2], s, 64);
    }
    const float F = 128.0f / 3.0f;
    float gcx = F * (ax[0] + ax[1]);
    float gcy = F * (ay[0] + ay[2]);
    float gcz = F * (ay[1] + ax[2]);

    // ---- epilogue ----
    const float beta = betap[0];
    float olev[L_][4];
    #pragma unroll
    for (int l = 0; l < L_; ++l) {
        float4 ov = *(const float4*)&o_s[wave][4 * l];
        olev[l][0] = ov.x; olev[l][1] = ov.y;
        olev[l][2] = ov.z; olev[l][3] = ov.w;
    }

    float r    = sqrtf(cx * cx + cy * cy + cz * cz);
    float smpl = r - 0.5f;
    float delta = 0.f;
    #pragma unroll
    for (int l = 0; l < L_; ++l) delta += olev[l][0];
    float sdf = smpl + delta;

    float ls[L_], sigma = 0.f;
    #pragma unroll
    for (int l = 0; l < L_; ++l) {
        float s = olev[l][0] + smpl;
        ls[l] = (1.0f / (1.0f + expf(s / beta))) / beta;
        sigma += ls[l];
    }
    float inv = 1.0f / (sigma + 1e-8f);
    float sem[L_];
    #pragma unroll
    for (int l = 0; l < L_; ++l) sem[l] = ls[l] * inv;

    float r0 = 0.f, r1 = 0.f, r2 = 0.f;
    #pragma unroll
    for (int l = 0; l < L_; ++l) {
        r0 = fmaf(olev[l][1], sem[l], r0);
        r1 = fmaf(olev[l][2], sem[l], r1);
        r2 = fmaf(olev[l][3], sem[l], r2);
    }
    float rgb0 = (1.0f / (1.0f + expf(-r0))) * 1.002f - 0.001f;
    float rgb1 = (1.0f / (1.0f + expf(-r1))) * 1.002f - 0.001f;
    float rgb2 = (1.0f / (1.0f + expf(-r2))) * 1.002f - 0.001f;

    float rinv = 1.0f / (r + 1e-8f);
    if (lane < 17) {
        float v =
            (lane == 0)  ? sdf :
            (lane == 1)  ? sigma :
            (lane == 2)  ? rgb0 :
            (lane == 3)  ? rgb1 :
            (lane == 4)  ? rgb2 :
            (lane == 5)  ? sem[0] :
            (lane == 6)  ? sem[1] :
            (lane == 7)  ? sem[2] :
            (lane == 8)  ? sem[3] :
            (lane == 9)  ? sem[4] :
            (lane == 10) ? sem[5] :
            (lane == 11) ? gcx + cx * rinv :
            (lane == 12) ? gcy + cy * rinv :
            (lane == 13) ? gcz + cz * rinv :
            (lane == 14) ? gcx :
            (lane == 15) ? gcy : gcz;
        out[(size_t)point * 17 + lane] = v;
    }
}

extern "C" void kernel_launch(void* const* d_in, const int* in_sizes, int n_in,
                              void* d_out, int out_size, void* d_ws, size_t ws_size,
                              hipStream_t stream)
{
    const float* planes = (const float*)d_in[0];
    const float* coords = (const float*)d_in[1];
    const float* w1     = (const float*)d_in[2];
    const float* b1     = (const float*)d_in[3];
    const float* w2     = (const float*)d_in[4];
    const float* b2     = (const float*)d_in[5];
    const float* beta   = (const float*)d_in[6];
    float* out = (float*)d_out;

    const size_t need = (size_t)6 * 65536 * C_ * sizeof(unsigned short); // 151 MB
    const int nblocks = 131072 / 4;   // 4 waves/block, 1 point/wave
    if (ws_size >= need) {
        unsigned short* tp = (unsigned short*)d_ws;
        transpose_kernel<<<6 * 2048, 256, 0, stream>>>(planes, tp);
        point_kernel<true><<<nblocks, 256, 0, stream>>>(
            tp, nullptr, coords, w1, b1, w2, b2, beta, out);
    } else {
        point_kernel<false><<<nblocks, 256, 0, stream>>>(
            nullptr, planes, coords, w1, b1, w2, b2, beta, out);
    }
}